// Round 7
// baseline (315.648 us; speedup 1.0000x reference)
//
#include <hip/hip_runtime.h>
#include <hip/hip_bf16.h>
#include <math.h>

#define BB 8192
#define NF 1024
#define KKc 2016
#define DD 64

typedef unsigned short u16;
typedef __attribute__((ext_vector_type(4))) float f32x4;
typedef __attribute__((ext_vector_type(4))) unsigned int u32x4;
typedef __attribute__((ext_vector_type(8))) short s16x8;
typedef __attribute__((ext_vector_type(8))) unsigned short u16x8;

__device__ __forceinline__ u16 bf16_rne(float f) {
  unsigned u = __float_as_uint(f);
  return (u16)((u + 0x7fffu + ((u >> 16) & 1u)) >> 16);
}

union BF2U { __hip_bfloat162 b; unsigned u; };

__device__ __forceinline__ unsigned pk_hi(float a, float b, float& fa, float& fb) {
  BF2U r; r.b = __float22bfloat162_rn(make_float2(a, b));
  float2 f = __bfloat1622float2(r.b);
  fa = f.x; fb = f.y;
  return r.u;
}
__device__ __forceinline__ unsigned pk(float a, float b) {
  BF2U r; r.b = __float22bfloat162_rn(make_float2(a, b));
  return r.u;
}

__device__ __forceinline__ void split4(const float t0, const float t1, const float t2,
                                       const float t3, uint2& h, uint2& l) {
  float f0, f1, f2, f3;
  h.x = pk_hi(t0, t1, f0, f1);
  h.y = pk_hi(t2, t3, f2, f3);
  l.x = pk(t0 - f0, t1 - f1);
  l.y = pk(t2 - f2, t3 - f3);
}

// ---- DPP cross-lane xor helpers (pure VALU, no LDS pipe) ----
template<int CTRL>
__device__ __forceinline__ float dpp_f(float v) {
  return __int_as_float(__builtin_amdgcn_mov_dpp(__float_as_int(v), CTRL, 0xF, 0xF, false));
}
__device__ __forceinline__ float dpp_xor8(float v) { return dpp_f<0x128>(v); }          // row_ror:8
__device__ __forceinline__ float dpp_xor4(float v) { return dpp_f<0x141>(dpp_f<0x1B>(v)); } // half_mirror o quad[3210]
__device__ __forceinline__ float dpp_xor2(float v) { return dpp_f<0x4E>(v); }           // quad_perm [2,3,0,1]
__device__ __forceinline__ float dpp_xor1(float v) { return dpp_f<0xB1>(v); }           // quad_perm [1,0,3,2]

#define XCH(A, B, M, XORF) { const float cA = XORF(B); const float cB = XORF(A); \
  A = (l & M) ? cA : A;  B = (l & M) ? B : cB; }

// transpose a 16x16 MFMA C-tile: in: lane(g=l>>4,q=l&15), regs i -> element(row g*4+i, col q)
// out: lane holds row (l>>2), cols (l&3)*4 + reg  (contiguous col quad per lane)
__device__ __forceinline__ void transpose16(float t[4], int l) {
  XCH(t[0], t[2], 8, dpp_xor8); XCH(t[1], t[3], 8, dpp_xor8);
  XCH(t[0], t[1], 4, dpp_xor4); XCH(t[2], t[3], 4, dpp_xor4);
  XCH(t[0], t[2], 2, dpp_xor2); XCH(t[1], t[3], 2, dpp_xor2);
  XCH(t[0], t[1], 1, dpp_xor1); XCH(t[2], t[3], 1, dpp_xor1);
}

// ---------------- Prepass A: xh/xl = split(silu(x)) ----------------
__global__ __launch_bounds__(256)
void silu_split_kernel(const float* __restrict__ x, u16* __restrict__ xh, u16* __restrict__ xl) {
  const int idx = blockIdx.x * 256 + threadIdx.x;
  float4 vv = ((const float4*)x)[idx];
  float a[4] = {vv.x, vv.y, vv.z, vv.w};
  u16 h[4], lo[4];
#pragma unroll
  for (int i = 0; i < 4; i++) {
    const float s = a[i] / (1.f + __expf(-a[i]));
    const u16 hh = bf16_rne(s);
    h[i] = hh;
    lo[i] = bf16_rne(s - __uint_as_float(((unsigned)hh) << 16));
  }
  ((ushort4*)xh)[idx] = make_ushort4(h[0], h[1], h[2], h[3]);
  ((ushort4*)xl)[idx] = make_ushort4(lo[0], lo[1], lo[2], lo[3]);
}

// ---------------- Prepass B: wh/wl = split(W), padded to 2048 rows ----------------
__global__ __launch_bounds__(256)
void wsplit_kernel(const float* __restrict__ W, u16* __restrict__ wh, u16* __restrict__ wl) {
  const int idx = blockIdx.x * 256 + threadIdx.x;
  const int row = idx >> 8;
  float4 vv = make_float4(0.f, 0.f, 0.f, 0.f);
  if (row < KKc) vv = ((const float4*)W)[idx];
  float a[4] = {vv.x, vv.y, vv.z, vv.w};
  u16 h[4], lo[4];
#pragma unroll
  for (int i = 0; i < 4; i++) {
    const u16 hh = bf16_rne(a[i]);
    h[i] = hh;
    lo[i] = bf16_rne(a[i] - __uint_as_float(((unsigned)hh) << 16));
  }
  ((ushort4*)wh)[idx] = make_ushort4(h[0], h[1], h[2], h[3]);
  ((ushort4*)wl)[idx] = make_ushort4(lo[0], lo[1], lo[2], lo[3]);
}

// ---------------- Kernel 1: v = silu(x)@W^T + b via split-bf16 MFMA ----------------
typedef __attribute__((address_space(1))) const unsigned int gu32;
typedef __attribute__((address_space(3))) unsigned int lu32;

__device__ __forceinline__ void gload_lds16(const void* g, void* l) {
  __builtin_amdgcn_global_load_lds((gu32*)g, (lu32*)l, 16, 0, 0);
}

__device__ __forceinline__ s16x8 frag_row32(const u16* T, int row, int kc) {
  const int c = kc ^ ((row >> 1) & 3);
  return *(const s16x8*)(T + row * 32 + c * 8);
}

__global__ __launch_bounds__(256, 3)
void gemm_mfma_kernel(const u16* __restrict__ xh, const u16* __restrict__ xl,
                      const u16* __restrict__ wh, const u16* __restrict__ wl,
                      const float* __restrict__ bias, float* __restrict__ v) {
  __shared__ __align__(16) u16 Ah[128 * 32];
  __shared__ __align__(16) u16 Al[128 * 32];
  __shared__ __align__(16) u16 Bh[128 * 32];
  __shared__ __align__(16) u16 Bl[128 * 32];
  const int tid = threadIdx.x;
  const int l = tid & 63, w = tid >> 6;
  const int wi = w >> 1, wj = w & 1;
  const int m0 = blockIdx.y * 128;
  const int n0 = blockIdx.x * 128;
  const int kc = l >> 4, lr = l & 15;

  const int row0 = (w < 2) ? m0 : n0;
  const u16* P = (w == 0) ? xh : (w == 1) ? xl : (w == 2) ? wh : wl;
  u16* T = (w == 0) ? Ah : (w == 1) ? Al : (w == 2) ? Bh : Bl;

  f32x4 acc[4][4];
  const f32x4 zz = {0.f, 0.f, 0.f, 0.f};
#pragma unroll
  for (int a = 0; a < 4; a++)
#pragma unroll
    for (int b = 0; b < 4; b++) acc[a][b] = zz;

  for (int k0 = 0; k0 < NF; k0 += 32) {
#pragma unroll
    for (int c8 = 0; c8 < 8; c8++) {
      const int slot = c8 * 64 + l;
      const int r = slot >> 2;
      const int c = (slot & 3) ^ ((r >> 1) & 3);
      gload_lds16(P + (size_t)(row0 + r) * NF + k0 + c * 8, T + c8 * 512);
    }
    __syncthreads();

    s16x8 fah[4], fal[4];
#pragma unroll
    for (int a = 0; a < 4; a++) {
      const int ra = wi * 64 + a * 16 + lr;
      fah[a] = frag_row32(Ah, ra, kc);
      fal[a] = frag_row32(Al, ra, kc);
    }
#pragma unroll
    for (int b = 0; b < 4; b++) {
      const int rb = wj * 64 + b * 16 + lr;
      const s16x8 fbh = frag_row32(Bh, rb, kc);
      const s16x8 fbl = frag_row32(Bl, rb, kc);
#pragma unroll
      for (int a = 0; a < 4; a++) {
        acc[a][b] = __builtin_amdgcn_mfma_f32_16x16x32_bf16(fah[a], fbh, acc[a][b], 0, 0, 0);
        acc[a][b] = __builtin_amdgcn_mfma_f32_16x16x32_bf16(fah[a], fbl, acc[a][b], 0, 0, 0);
        acc[a][b] = __builtin_amdgcn_mfma_f32_16x16x32_bf16(fal[a], fbh, acc[a][b], 0, 0, 0);
      }
    }
    __syncthreads();
  }

  const int grp = l >> 4;
#pragma unroll
  for (int b = 0; b < 4; b++) {
    const int n = n0 + wj * 64 + b * 16 + lr;
    if (n < KKc) {
      const float bb = bias[n];
#pragma unroll
      for (int a = 0; a < 4; a++) {
        const int mbase = m0 + wi * 64 + a * 16 + grp * 4;
#pragma unroll
        for (int i = 0; i < 4; i++)
          v[(size_t)(mbase + i) * KKc + n] = acc[a][b][i] + bb;
      }
    }
  }
}

// ---------------- Fallback fp32 GEMM (if ws too small) ----------------
#define BM 128
#define BN 128
#define BKr 16
#define XST 132

__global__ __launch_bounds__(256, 2)
void gemm_silu_kernel(const float* __restrict__ x, const float* __restrict__ W,
                      const float* __restrict__ bias, float* __restrict__ v) {
  __shared__ float xs[BKr * XST];
  __shared__ float wl[BKr * XST];
  const int tid = threadIdx.x;
  const int tx = tid & 15, ty = tid >> 4;
  const int c0g = blockIdx.x * BN;
  const int m0 = blockIdx.y * BM;
  const int lrow = tid >> 2;
  const int lu = (tid & 3) << 2;

  float acc[2][2][4][4];
#pragma unroll
  for (int a = 0; a < 2; a++)
#pragma unroll
    for (int b = 0; b < 2; b++)
#pragma unroll
      for (int i = 0; i < 4; i++)
#pragma unroll
        for (int j = 0; j < 4; j++) acc[a][b][i][j] = 0.f;

  for (int n0 = 0; n0 < NF; n0 += BKr) {
#pragma unroll
    for (int p = 0; p < 2; p++) {
      const int row = lrow + 64 * p;
      float4 xv = *(const float4*)(x + (size_t)(m0 + row) * NF + n0 + lu);
      float xa[4] = {xv.x, xv.y, xv.z, xv.w};
#pragma unroll
      for (int u = 0; u < 4; u++) {
        const float val = xa[u];
        xs[(lu + u) * XST + row] = val / (1.f + __expf(-val));
      }
      const int wr = c0g + row;
      float4 wv = make_float4(0.f, 0.f, 0.f, 0.f);
      if (wr < KKc) wv = *(const float4*)(W + (size_t)wr * NF + n0 + lu);
      float wa[4] = {wv.x, wv.y, wv.z, wv.w};
#pragma unroll
      for (int u = 0; u < 4; u++) wl[(lu + u) * XST + row] = wa[u];
    }
    __syncthreads();
#pragma unroll
    for (int k0 = 0; k0 < BKr; k0 += 4) {
#pragma unroll
      for (int kk = 0; kk < 4; kk++) {
        const float* xr = xs + (k0 + kk) * XST;
        const float* wr_ = wl + (k0 + kk) * XST;
        float4 t;
        t = *(const float4*)(xr + 4 * ty);       float a0[4] = {t.x, t.y, t.z, t.w};
        t = *(const float4*)(xr + 64 + 4 * ty);  float a1[4] = {t.x, t.y, t.z, t.w};
        t = *(const float4*)(wr_ + 4 * tx);      float b0[4] = {t.x, t.y, t.z, t.w};
        t = *(const float4*)(wr_ + 64 + 4 * tx); float b1[4] = {t.x, t.y, t.z, t.w};
#pragma unroll
        for (int i = 0; i < 4; i++)
#pragma unroll
          for (int j = 0; j < 4; j++) {
            acc[0][0][i][j] = fmaf(a0[i], b0[j], acc[0][0][i][j]);
            acc[0][1][i][j] = fmaf(a0[i], b1[j], acc[0][1][i][j]);
            acc[1][0][i][j] = fmaf(a1[i], b0[j], acc[1][0][i][j]);
            acc[1][1][i][j] = fmaf(a1[i], b1[j], acc[1][1][i][j]);
          }
      }
    }
    __syncthreads();
  }
#pragma unroll
  for (int rb = 0; rb < 2; rb++)
#pragma unroll
    for (int ii = 0; ii < 4; ii++) {
      const int row = m0 + rb * 64 + 4 * ty + ii;
#pragma unroll
      for (int cb = 0; cb < 2; cb++) {
        const int c = c0g + cb * 64 + 4 * tx;
        if (c < KKc) {
          float4 bb = *(const float4*)(bias + c);
          float4 o;
          o.x = acc[rb][cb][ii][0] + bb.x;
          o.y = acc[rb][cb][ii][1] + bb.y;
          o.z = acc[rb][cb][ii][2] + bb.z;
          o.w = acc[rb][cb][ii][3] + bb.w;
          *(float4*)(v + (size_t)row * KKc + c) = o;
        }
      }
    }
}

// ---------------- Kernel 2: R = expm(skew(v_row)) — separate hi/lo bf16 planes ----------------
// LDS layout per plane: u16[64][64], 16B chunk swizzle: chunk' = chunk ^ (row&7).

union FragX { u16x8 u; s16x8 s; u32x4 d; };

__device__ __forceinline__ s16x8 fragld(const u16* P, int row, int chunk) {
  return *(const s16x8*)(P + ((row << 6) | ((chunk ^ (row & 7)) << 3)));
}

__device__ __forceinline__ s16x8 fneg(s16x8 f) {
  FragX x; x.s = f;
  x.d ^= (u32x4){0x80008000u, 0x80008000u, 0x80008000u, 0x80008000u};
  return x.s;
}

// acc += A*B (2x2 16x16 tiles/wave); B row-read (symmetric / col-copy / skew+NEGB)
template<int NPASS, bool NEGB>
__device__ __forceinline__ void mat_mm(const u16* APh, const u16* APl,
                                       const u16* BPh, const u16* BPl,
                                       f32x4 acc[2][2], int wi, int wj, int g, int lr) {
#pragma unroll
  for (int kb = 0; kb < 2; kb++) {
    const int ch = (kb << 2) | g;
    s16x8 bh[2], bl[2];
#pragma unroll
    for (int b = 0; b < 2; b++) {
      const int n = wj * 32 + b * 16 + lr;
      bh[b] = fragld(BPh, n, ch);
      if (NEGB) bh[b] = fneg(bh[b]);
      if (NPASS == 3) {
        bl[b] = fragld(BPl, n, ch);
        if (NEGB) bl[b] = fneg(bl[b]);
      }
    }
#pragma unroll
    for (int a = 0; a < 2; a++) {
      const int r = wi * 32 + a * 16 + lr;
      const s16x8 ah = fragld(APh, r, ch);
      s16x8 al;
      if (NPASS == 3) al = fragld(APl, r, ch);
#pragma unroll
      for (int b = 0; b < 2; b++) {
        acc[a][b] = __builtin_amdgcn_mfma_f32_16x16x32_bf16(ah, bh[b], acc[a][b], 0, 0, 0);
        if (NPASS == 3) {
          acc[a][b] = __builtin_amdgcn_mfma_f32_16x16x32_bf16(ah, bl[b], acc[a][b], 0, 0, 0);
          acc[a][b] = __builtin_amdgcn_mfma_f32_16x16x32_bf16(al, bh[b], acc[a][b], 0, 0, 0);
        }
      }
    }
  }
}

// fused 1-pass: acc6 += A4*A2, acc8 += A4*A4 (shared A-frags)
__device__ __forceinline__ void mat_mm68(const u16* A4h, const u16* A2h,
                                         f32x4 acc6[2][2], f32x4 acc8[2][2],
                                         int wi, int wj, int g, int lr) {
#pragma unroll
  for (int kb = 0; kb < 2; kb++) {
    const int ch = (kb << 2) | g;
    s16x8 b2[2], b4[2];
#pragma unroll
    for (int b = 0; b < 2; b++) {
      const int n = wj * 32 + b * 16 + lr;
      b2[b] = fragld(A2h, n, ch);
      b4[b] = fragld(A4h, n, ch);
    }
#pragma unroll
    for (int a = 0; a < 2; a++) {
      const int r = wi * 32 + a * 16 + lr;
      const s16x8 ah = fragld(A4h, r, ch);
#pragma unroll
      for (int b = 0; b < 2; b++) {
        acc6[a][b] = __builtin_amdgcn_mfma_f32_16x16x32_bf16(ah, b2[b], acc6[a][b], 0, 0, 0);
        acc8[a][b] = __builtin_amdgcn_mfma_f32_16x16x32_bf16(ah, b4[b], acc8[a][b], 0, 0, 0);
      }
    }
  }
}

// write acc as [col][row] copy (b64 contiguous). For SYMMETRIC matrices this IS row-major.
__device__ __forceinline__ void pack_col(u16* Ch, u16* Cl, const f32x4 acc[2][2],
                                         int wi, int wj, int g, int lr) {
#pragma unroll
  for (int a = 0; a < 2; a++) {
    const int r0 = wi * 32 + a * 16 + g * 4;
#pragma unroll
    for (int b = 0; b < 2; b++) {
      const int c = wj * 32 + b * 16 + lr;
      uint2 h, l;
      split4(acc[a][b][0], acc[a][b][1], acc[a][b][2], acc[a][b][3], h, l);
      const int ad = (c << 6) | (((((r0 >> 3)) ^ (c & 7)) << 3) | (r0 & 7));
      *(uint2*)(Ch + ad) = h;
      *(uint2*)(Cl + ad) = l;
    }
  }
}

// write acc as ROW-major copy via in-register DPP transpose -> b64 writes only
__device__ __forceinline__ void pack_rowT(u16* Rh, u16* Rl, const f32x4 acc[2][2],
                                          int wi, int wj, int l) {
#pragma unroll
  for (int a = 0; a < 2; a++)
#pragma unroll
    for (int b = 0; b < 2; b++) {
      float t[4] = {acc[a][b][0], acc[a][b][1], acc[a][b][2], acc[a][b][3]};
      transpose16(t, l);
      const int row = wi * 32 + a * 16 + (l >> 2);
      const int c0 = wj * 32 + b * 16 + (l & 3) * 4;
      uint2 h, lo;
      split4(t[0], t[1], t[2], t[3], h, lo);
      const int ad = (row << 6) | ((((c0 >> 3) ^ (row & 7)) << 3) | (c0 & 7));
      *(uint2*)(Rh + ad) = h;
      *(uint2*)(Rl + ad) = lo;
    }
}

__global__ __launch_bounds__(256, 3)
void expm_kernel(const float* __restrict__ v, float* __restrict__ out) {
  __shared__ __align__(16) u16 Ahs[4096], Als[4096];
  __shared__ __align__(16) u16 P1h[4096], P1l[4096];
  __shared__ __align__(16) u16 P2h[4096], P2l[4096];
  __shared__ float red[4];
  const int tid = threadIdx.x;
  const int bid = blockIdx.x;
  const int l = tid & 63, w = tid >> 6;
  const int g = l >> 4, lr = l & 15;
  const int wi = w >> 1, wj = w & 1;

  // 1. stage v row into P2h (2016 floats, 8064B fits the 8KB plane)
  {
    float* vb = (float*)P2h;
    const float* vr = v + (size_t)bid * KKc;
    for (int i = tid; i < KKc; i += 256) vb[i] = vr[i];
  }
  __syncthreads();

  // 2. build skew A (UNSCALED) into Ah/Al planes via cvt_pk
  {
    const float* vb = (const float*)P2h;
    const int arow = tid >> 2, q = tid & 3;
    float va[16];
#pragma unroll
    for (int j = 0; j < 16; j++) {
      const int c = q * 16 + j;
      float val = 0.f;
      if (arow < c)      val =  vb[(arow * (127 - arow)) / 2 + c - arow - 1];
      else if (arow > c) val = -vb[(c * (127 - c)) / 2 + arow - c - 1];
      va[j] = val;
    }
#pragma unroll
    for (int cc = 0; cc < 2; cc++) {
      const int ch = 2 * q + cc;
      const int ad = (arow << 6) | ((ch ^ (arow & 7)) << 3);
      unsigned hw[4], lw[4];
#pragma unroll
      for (int p = 0; p < 4; p++) {
        const float a = va[cc * 8 + 2 * p], b = va[cc * 8 + 2 * p + 1];
        float fa, fb;
        hw[p] = pk_hi(a, b, fa, fb);
        lw[p] = pk(a - fa, b - fb);
      }
      *(u32x4*)(Ahs + ad) = (u32x4){hw[0], hw[1], hw[2], hw[3]};
      *(u32x4*)(Als + ad) = (u32x4){lw[0], lw[1], lw[2], lw[3]};
    }
  }
  __syncthreads();

  const f32x4 zz = {0.f, 0.f, 0.f, 0.f};
  f32x4 acc[2][2];

  // 3. A2 = A*A (B-frag = -(row-read of skew A))
  acc[0][0] = zz; acc[0][1] = zz; acc[1][0] = zz; acc[1][1] = zz;
  mat_mm<3, true>(Ahs, Als, Ahs, Als, acc, wi, wj, g, lr);
  f32x4 rA2[2][2];
  rA2[0][0] = acc[0][0]; rA2[0][1] = acc[0][1]; rA2[1][0] = acc[1][0]; rA2[1][1] = acc[1][1];
  pack_col(P1h, P1l, acc, wi, wj, g, lr);   // A2 symmetric -> col-copy == row-major
  __syncthreads();

  // 4. A4 = A2*A2
  acc[0][0] = zz; acc[0][1] = zz; acc[1][0] = zz; acc[1][1] = zz;
  mat_mm<3, false>(P1h, P1l, P1h, P1l, acc, wi, wj, g, lr);
  f32x4 rA4[2][2];
  rA4[0][0] = acc[0][0]; rA4[0][1] = acc[0][1]; rA4[1][0] = acc[1][0]; rA4[1][1] = acc[1][1];
  pack_col(P2h, P2l, acc, wi, wj, g, lr);   // A4 symmetric (v-staging dead)
  __syncthreads();

  // 5. A6 = A4*A2, A8 = A4*A4 (fused 1-pass, acc-only)
  f32x4 acc6[2][2], acc8[2][2];
  acc6[0][0] = zz; acc6[0][1] = zz; acc6[1][0] = zz; acc6[1][1] = zz;
  acc8[0][0] = zz; acc8[0][1] = zz; acc8[1][0] = zz; acc8[1][1] = zz;
  mat_mm68(P2h, P1h, acc6, acc8, wi, wj, g, lr);

  // 6. s from ||A^8||_F with theta = 1.5 (lambda_max <= ||A^8||_F^{1/8})
  {
    float fs = 0.f;
#pragma unroll
    for (int a = 0; a < 2; a++)
#pragma unroll
      for (int b = 0; b < 2; b++)
#pragma unroll
        for (int i = 0; i < 4; i++) fs = fmaf(acc8[a][b][i], acc8[a][b][i], fs);
#pragma unroll
    for (int k = 1; k < 64; k <<= 1) fs += __shfl_xor(fs, k, 64);
    if (l == 0) red[w] = fs;
  }
  __syncthreads();   // also: all P1/P2 reads (A6/A8) done before S3' overwrite below

  const float nf16 = red[0] + red[1] + red[2] + red[3];  // = ||A^8||_F^2
  int s = 0;
  if (nf16 > 1.f) {
    // s = ceil(log2(lambda) - log2(1.5)); lambda = nf16^{1/16}
    s = (int)ceilf(0.0625f * log2f(nf16) - 0.58496f);
    if (s < 0) s = 0;
    if (s > 15) s = 15;
  }
  const float t = exp2f(-(float)s);
  const float t2 = t * t, t4 = t2 * t2, t6 = t4 * t2, t8 = t4 * t4;
  const float e2 = 0.5f * t2, e4 = t4 / 24.f, e6 = t6 / 720.f, e8 = t8 / 40320.f;
  const float o1 = t, o3 = t * t2 / 6.f, o5 = t * t4 / 120.f, o7 = t * t6 / 5040.f;

  // 7. fold E and S3' from A2,A4,A6,A8 (X^{2k} = t^{2k} A^{2k})
  f32x4 rE[2][2], rS3[2][2];
#pragma unroll
  for (int a = 0; a < 2; a++)
#pragma unroll
    for (int b = 0; b < 2; b++)
#pragma unroll
      for (int i = 0; i < 4; i++) {
        const int row = wi * 32 + a * 16 + g * 4 + i;
        const int col = wj * 32 + b * 16 + lr;
        const float dg = (row == col) ? 1.f : 0.f;
        rE[a][b][i]  = dg + e2 * rA2[a][b][i] + e4 * rA4[a][b][i]
                          + e6 * acc6[a][b][i] + e8 * acc8[a][b][i];
        rS3[a][b][i] = o1 * dg + o3 * rA2[a][b][i] + o5 * rA4[a][b][i]
                              + o7 * acc6[a][b][i];
      }

  pack_col(P1h, P1l, rS3, wi, wj, g, lr);  // S3' symmetric -> P1
  __syncthreads();

  // 8. R0 = E + A * S3'   (acc init = E; S3' carries the t scale)
  acc[0][0] = rE[0][0]; acc[0][1] = rE[0][1]; acc[1][0] = rE[1][0]; acc[1][1] = rE[1][1];
  mat_mm<3, false>(Ahs, Als, P1h, P1l, acc, wi, wj, g, lr);
  __syncthreads();   // all reads of Ah/P1 done before squaring overwrites

  // 9. s squarings: row-copy (DPP-transposed, b64) in P2, col-copy in Ahs
  for (int it = 0; it < s; it++) {
    pack_rowT(P2h, P2l, acc, wi, wj, l);
    pack_col(Ahs, Als, acc, wi, wj, g, lr);
    __syncthreads();
    acc[0][0] = zz; acc[0][1] = zz; acc[1][0] = zz; acc[1][1] = zz;
    mat_mm<3, false>(P2h, P2l, Ahs, Als, acc, wi, wj, g, lr);
    __syncthreads();
  }

  // 10. store result: transpose -> coalesced float4 stores
  float* ob = out + (size_t)bid * 4096;
#pragma unroll
  for (int a = 0; a < 2; a++)
#pragma unroll
    for (int b = 0; b < 2; b++) {
      float t[4] = {acc[a][b][0], acc[a][b][1], acc[a][b][2], acc[a][b][3]};
      transpose16(t, l);
      const int row = wi * 32 + a * 16 + (l >> 2);
      const int c0 = wj * 32 + b * 16 + (l & 3) * 4;
      *(float4*)(ob + row * 64 + c0) = make_float4(t[0], t[1], t[2], t[3]);
    }
}

extern "C" void kernel_launch(void* const* d_in, const int* in_sizes, int n_in,
                              void* d_out, int out_size, void* d_ws, size_t ws_size,
                              hipStream_t stream) {
  const float* x = (const float*)d_in[0];
  const float* W = (const float*)d_in[1];
  const float* bias = (const float*)d_in[2];
  float* out = (float*)d_out;
  char* ws = (char*)d_ws;
  float* v = (float*)ws;

  const size_t V_BYTES  = (size_t)BB * KKc * 4;
  const size_t XH_ELEMS = (size_t)BB * NF;
  const size_t WH_ELEMS = (size_t)2048 * NF;
  const size_t NEED = V_BYTES + 2 * XH_ELEMS * 2 + 2 * WH_ELEMS * 2;

  if (ws_size >= NEED) {
    u16* xh = (u16*)(ws + V_BYTES);
    u16* xl = xh + XH_ELEMS;
    u16* wh = xl + XH_ELEMS;
    u16* wlp = wh + WH_ELEMS;
    silu_split_kernel<<<dim3(BB * NF / 4 / 256), dim3(256), 0, stream>>>(x, xh, xl);
    wsplit_kernel<<<dim3(2048 * NF / 4 / 256), dim3(256), 0, stream>>>(W, wh, wlp);
    gemm_mfma_kernel<<<dim3(16, 64), dim3(256), 0, stream>>>(xh, xl, wh, wlp, bias, v);
  } else {
    dim3 g1((KKc + BN - 1) / BN, BB / BM);
    gemm_silu_kernel<<<g1, dim3(256), 0, stream>>>(x, W, bias, v);
  }
  expm_kernel<<<dim3(BB), dim3(256), 0, stream>>>(v, out);
}

// Round 8
// 246.240 us; speedup vs baseline: 1.2819x; 1.2819x over previous
//
#include <hip/hip_runtime.h>
#include <hip/hip_bf16.h>
#include <hip/hip_fp16.h>
#include <math.h>

#define BB 8192
#define NF 1024
#define KKc 2016
#define DD 64

typedef unsigned short u16;
typedef __attribute__((ext_vector_type(4))) float f32x4;
typedef __attribute__((ext_vector_type(4))) unsigned int u32x4;
typedef __attribute__((ext_vector_type(8))) short s16x8;
typedef __attribute__((ext_vector_type(8))) _Float16 f16x8;
typedef __attribute__((ext_vector_type(8))) unsigned short u16x8;

__device__ __forceinline__ u16 bf16_rne(float f) {
  unsigned u = __float_as_uint(f);
  return (u16)((u + 0x7fffu + ((u >> 16) & 1u)) >> 16);
}

union BF2U { __hip_bfloat162 b; unsigned u; };
union H2U { __half2 h; unsigned u; };

__device__ __forceinline__ unsigned pk_hi(float a, float b, float& fa, float& fb) {
  BF2U r; r.b = __float22bfloat162_rn(make_float2(a, b));
  float2 f = __bfloat1622float2(r.b);
  fa = f.x; fb = f.y;
  return r.u;
}
__device__ __forceinline__ unsigned pk(float a, float b) {
  BF2U r; r.b = __float22bfloat162_rn(make_float2(a, b));
  return r.u;
}
__device__ __forceinline__ unsigned pkh(float a, float b) {
  H2U r; r.h = __float22half2_rn(make_float2(a, b));
  return r.u;
}

__device__ __forceinline__ void split4(const float t0, const float t1, const float t2,
                                       const float t3, uint2& h, uint2& l) {
  float f0, f1, f2, f3;
  h.x = pk_hi(t0, t1, f0, f1);
  h.y = pk_hi(t2, t3, f2, f3);
  l.x = pk(t0 - f0, t1 - f1);
  l.y = pk(t2 - f2, t3 - f3);
}

// ---- DPP cross-lane xor helpers (final-store transpose only) ----
template<int CTRL>
__device__ __forceinline__ float dpp_f(float v) {
  return __int_as_float(__builtin_amdgcn_mov_dpp(__float_as_int(v), CTRL, 0xF, 0xF, false));
}
__device__ __forceinline__ float dpp_xor8(float v) { return dpp_f<0x128>(v); }
__device__ __forceinline__ float dpp_xor4(float v) { return dpp_f<0x141>(dpp_f<0x1B>(v)); }
__device__ __forceinline__ float dpp_xor2(float v) { return dpp_f<0x4E>(v); }
__device__ __forceinline__ float dpp_xor1(float v) { return dpp_f<0xB1>(v); }

#define XCH(A, B, M, XORF) { const float cA = XORF(B); const float cB = XORF(A); \
  A = (l & M) ? cA : A;  B = (l & M) ? B : cB; }

__device__ __forceinline__ void transpose16(float t[4], int l) {
  XCH(t[0], t[2], 8, dpp_xor8); XCH(t[1], t[3], 8, dpp_xor8);
  XCH(t[0], t[1], 4, dpp_xor4); XCH(t[2], t[3], 4, dpp_xor4);
  XCH(t[0], t[2], 2, dpp_xor2); XCH(t[1], t[3], 2, dpp_xor2);
  XCH(t[0], t[1], 1, dpp_xor1); XCH(t[2], t[3], 1, dpp_xor1);
}

// ---------------- Prepass A: xh/xl = split(silu(x)) ----------------
__global__ __launch_bounds__(256)
void silu_split_kernel(const float* __restrict__ x, u16* __restrict__ xh, u16* __restrict__ xl) {
  const int idx = blockIdx.x * 256 + threadIdx.x;
  float4 vv = ((const float4*)x)[idx];
  float a[4] = {vv.x, vv.y, vv.z, vv.w};
  u16 h[4], lo[4];
#pragma unroll
  for (int i = 0; i < 4; i++) {
    const float s = a[i] / (1.f + __expf(-a[i]));
    const u16 hh = bf16_rne(s);
    h[i] = hh;
    lo[i] = bf16_rne(s - __uint_as_float(((unsigned)hh) << 16));
  }
  ((ushort4*)xh)[idx] = make_ushort4(h[0], h[1], h[2], h[3]);
  ((ushort4*)xl)[idx] = make_ushort4(lo[0], lo[1], lo[2], lo[3]);
}

// ---------------- Prepass B: wh/wl = split(W), padded to 2048 rows ----------------
__global__ __launch_bounds__(256)
void wsplit_kernel(const float* __restrict__ W, u16* __restrict__ wh, u16* __restrict__ wl) {
  const int idx = blockIdx.x * 256 + threadIdx.x;
  const int row = idx >> 8;
  float4 vv = make_float4(0.f, 0.f, 0.f, 0.f);
  if (row < KKc) vv = ((const float4*)W)[idx];
  float a[4] = {vv.x, vv.y, vv.z, vv.w};
  u16 h[4], lo[4];
#pragma unroll
  for (int i = 0; i < 4; i++) {
    const u16 hh = bf16_rne(a[i]);
    h[i] = hh;
    lo[i] = bf16_rne(a[i] - __uint_as_float(((unsigned)hh) << 16));
  }
  ((ushort4*)wh)[idx] = make_ushort4(h[0], h[1], h[2], h[3]);
  ((ushort4*)wl)[idx] = make_ushort4(lo[0], lo[1], lo[2], lo[3]);
}

// ---------------- Kernel 1: v = silu(x)@W^T + b via split-bf16 MFMA ----------------
typedef __attribute__((address_space(1))) const unsigned int gu32;
typedef __attribute__((address_space(3))) unsigned int lu32;

__device__ __forceinline__ void gload_lds16(const void* g, void* l) {
  __builtin_amdgcn_global_load_lds((gu32*)g, (lu32*)l, 16, 0, 0);
}

__device__ __forceinline__ s16x8 frag_row32(const u16* T, int row, int kc) {
  const int c = kc ^ ((row >> 1) & 3);
  return *(const s16x8*)(T + row * 32 + c * 8);
}

__global__ __launch_bounds__(256, 3)
void gemm_mfma_kernel(const u16* __restrict__ xh, const u16* __restrict__ xl,
                      const u16* __restrict__ wh, const u16* __restrict__ wl,
                      const float* __restrict__ bias, float* __restrict__ v) {
  __shared__ __align__(16) u16 Ah[128 * 32];
  __shared__ __align__(16) u16 Al[128 * 32];
  __shared__ __align__(16) u16 Bh[128 * 32];
  __shared__ __align__(16) u16 Bl[128 * 32];
  const int tid = threadIdx.x;
  const int l = tid & 63, w = tid >> 6;
  const int wi = w >> 1, wj = w & 1;
  const int m0 = blockIdx.y * 128;
  const int n0 = blockIdx.x * 128;
  const int kc = l >> 4, lr = l & 15;

  const int row0 = (w < 2) ? m0 : n0;
  const u16* P = (w == 0) ? xh : (w == 1) ? xl : (w == 2) ? wh : wl;
  u16* T = (w == 0) ? Ah : (w == 1) ? Al : (w == 2) ? Bh : Bl;

  f32x4 acc[4][4];
  const f32x4 zz = {0.f, 0.f, 0.f, 0.f};
#pragma unroll
  for (int a = 0; a < 4; a++)
#pragma unroll
    for (int b = 0; b < 4; b++) acc[a][b] = zz;

  for (int k0 = 0; k0 < NF; k0 += 32) {
#pragma unroll
    for (int c8 = 0; c8 < 8; c8++) {
      const int slot = c8 * 64 + l;
      const int r = slot >> 2;
      const int c = (slot & 3) ^ ((r >> 1) & 3);
      gload_lds16(P + (size_t)(row0 + r) * NF + k0 + c * 8, T + c8 * 512);
    }
    __syncthreads();

    s16x8 fah[4], fal[4];
#pragma unroll
    for (int a = 0; a < 4; a++) {
      const int ra = wi * 64 + a * 16 + lr;
      fah[a] = frag_row32(Ah, ra, kc);
      fal[a] = frag_row32(Al, ra, kc);
    }
#pragma unroll
    for (int b = 0; b < 4; b++) {
      const int rb = wj * 64 + b * 16 + lr;
      const s16x8 fbh = frag_row32(Bh, rb, kc);
      const s16x8 fbl = frag_row32(Bl, rb, kc);
#pragma unroll
      for (int a = 0; a < 4; a++) {
        acc[a][b] = __builtin_amdgcn_mfma_f32_16x16x32_bf16(fah[a], fbh, acc[a][b], 0, 0, 0);
        acc[a][b] = __builtin_amdgcn_mfma_f32_16x16x32_bf16(fah[a], fbl, acc[a][b], 0, 0, 0);
        acc[a][b] = __builtin_amdgcn_mfma_f32_16x16x32_bf16(fal[a], fbh, acc[a][b], 0, 0, 0);
      }
    }
    __syncthreads();
  }

  const int grp = l >> 4;
#pragma unroll
  for (int b = 0; b < 4; b++) {
    const int n = n0 + wj * 64 + b * 16 + lr;
    if (n < KKc) {
      const float bb = bias[n];
#pragma unroll
      for (int a = 0; a < 4; a++) {
        const int mbase = m0 + wi * 64 + a * 16 + grp * 4;
#pragma unroll
        for (int i = 0; i < 4; i++)
          v[(size_t)(mbase + i) * KKc + n] = acc[a][b][i] + bb;
      }
    }
  }
}

// ---------------- Fallback fp32 GEMM (if ws too small) ----------------
#define BM 128
#define BN 128
#define BKr 16
#define XST 132

__global__ __launch_bounds__(256, 2)
void gemm_silu_kernel(const float* __restrict__ x, const float* __restrict__ W,
                      const float* __restrict__ bias, float* __restrict__ v) {
  __shared__ float xs[BKr * XST];
  __shared__ float wl[BKr * XST];
  const int tid = threadIdx.x;
  const int tx = tid & 15, ty = tid >> 4;
  const int c0g = blockIdx.x * BN;
  const int m0 = blockIdx.y * BM;
  const int lrow = tid >> 2;
  const int lu = (tid & 3) << 2;

  float acc[2][2][4][4];
#pragma unroll
  for (int a = 0; a < 2; a++)
#pragma unroll
    for (int b = 0; b < 2; b++)
#pragma unroll
      for (int i = 0; i < 4; i++)
#pragma unroll
        for (int j = 0; j < 4; j++) acc[a][b][i][j] = 0.f;

  for (int n0 = 0; n0 < NF; n0 += BKr) {
#pragma unroll
    for (int p = 0; p < 2; p++) {
      const int row = lrow + 64 * p;
      float4 xv = *(const float4*)(x + (size_t)(m0 + row) * NF + n0 + lu);
      float xa[4] = {xv.x, xv.y, xv.z, xv.w};
#pragma unroll
      for (int u = 0; u < 4; u++) {
        const float val = xa[u];
        xs[(lu + u) * XST + row] = val / (1.f + __expf(-val));
      }
      const int wr = c0g + row;
      float4 wv = make_float4(0.f, 0.f, 0.f, 0.f);
      if (wr < KKc) wv = *(const float4*)(W + (size_t)wr * NF + n0 + lu);
      float wa[4] = {wv.x, wv.y, wv.z, wv.w};
#pragma unroll
      for (int u = 0; u < 4; u++) wl[(lu + u) * XST + row] = wa[u];
    }
    __syncthreads();
#pragma unroll
    for (int k0 = 0; k0 < BKr; k0 += 4) {
#pragma unroll
      for (int kk = 0; kk < 4; kk++) {
        const float* xr = xs + (k0 + kk) * XST;
        const float* wr_ = wl + (k0 + kk) * XST;
        float4 t;
        t = *(const float4*)(xr + 4 * ty);       float a0[4] = {t.x, t.y, t.z, t.w};
        t = *(const float4*)(xr + 64 + 4 * ty);  float a1[4] = {t.x, t.y, t.z, t.w};
        t = *(const float4*)(wr_ + 4 * tx);      float b0[4] = {t.x, t.y, t.z, t.w};
        t = *(const float4*)(wr_ + 64 + 4 * tx); float b1[4] = {t.x, t.y, t.z, t.w};
#pragma unroll
        for (int i = 0; i < 4; i++)
#pragma unroll
          for (int j = 0; j < 4; j++) {
            acc[0][0][i][j] = fmaf(a0[i], b0[j], acc[0][0][i][j]);
            acc[0][1][i][j] = fmaf(a0[i], b1[j], acc[0][1][i][j]);
            acc[1][0][i][j] = fmaf(a1[i], b0[j], acc[1][0][i][j]);
            acc[1][1][i][j] = fmaf(a1[i], b1[j], acc[1][1][i][j]);
          }
      }
    }
    __syncthreads();
  }
#pragma unroll
  for (int rb = 0; rb < 2; rb++)
#pragma unroll
    for (int ii = 0; ii < 4; ii++) {
      const int row = m0 + rb * 64 + 4 * ty + ii;
#pragma unroll
      for (int cb = 0; cb < 2; cb++) {
        const int c = c0g + cb * 64 + 4 * tx;
        if (c < KKc) {
          float4 bb = *(const float4*)(bias + c);
          float4 o;
          o.x = acc[rb][cb][ii][0] + bb.x;
          o.y = acc[rb][cb][ii][1] + bb.y;
          o.z = acc[rb][cb][ii][2] + bb.z;
          o.w = acc[rb][cb][ii][3] + bb.w;
          *(float4*)(v + (size_t)row * KKc + c) = o;
        }
      }
    }
}

// ---------------- Kernel 2: expm(skew(v_row)) — mixed split-bf16 / fp16 ----------------
// Plane layout: u16[64][64]; 16B chunk swizzle chunk' = chunk ^ (row&7).

union FragX { u16x8 u; s16x8 s; u32x4 d; };
union F16U { s16x8 s; f16x8 h; };

__device__ __forceinline__ s16x8 fragld(const u16* P, int row, int chunk) {
  return *(const s16x8*)(P + ((row << 6) | ((chunk ^ (row & 7)) << 3)));
}

__device__ __forceinline__ s16x8 fneg(s16x8 f) {
  FragX x; x.s = f;
  x.d ^= (u32x4){0x80008000u, 0x80008000u, 0x80008000u, 0x80008000u};
  return x.s;
}

// split-bf16 3-pass (or hi-only): acc += A*B, B row-read
template<int NPASS, bool NEGB>
__device__ __forceinline__ void mat_mm(const u16* APh, const u16* APl,
                                       const u16* BPh, const u16* BPl,
                                       f32x4 acc[2][2], int wi, int wj, int g, int lr) {
#pragma unroll
  for (int kb = 0; kb < 2; kb++) {
    const int ch = (kb << 2) | g;
    s16x8 bh[2], bl[2];
#pragma unroll
    for (int b = 0; b < 2; b++) {
      const int n = wj * 32 + b * 16 + lr;
      bh[b] = fragld(BPh, n, ch);
      if (NEGB) bh[b] = fneg(bh[b]);
      if (NPASS == 3) {
        bl[b] = fragld(BPl, n, ch);
        if (NEGB) bl[b] = fneg(bl[b]);
      }
    }
#pragma unroll
    for (int a = 0; a < 2; a++) {
      const int r = wi * 32 + a * 16 + lr;
      const s16x8 ah = fragld(APh, r, ch);
      s16x8 al;
      if (NPASS == 3) al = fragld(APl, r, ch);
#pragma unroll
      for (int b = 0; b < 2; b++) {
        acc[a][b] = __builtin_amdgcn_mfma_f32_16x16x32_bf16(ah, bh[b], acc[a][b], 0, 0, 0);
        if (NPASS == 3) {
          acc[a][b] = __builtin_amdgcn_mfma_f32_16x16x32_bf16(ah, bl[b], acc[a][b], 0, 0, 0);
          acc[a][b] = __builtin_amdgcn_mfma_f32_16x16x32_bf16(al, bh[b], acc[a][b], 0, 0, 0);
        }
      }
    }
  }
}

// fp16 1-pass: acc += A*B, both row-read from single fp16 planes
__device__ __forceinline__ void mat_mm1h(const u16* AP, const u16* BP,
                                         f32x4 acc[2][2], int wi, int wj, int g, int lr) {
#pragma unroll
  for (int kb = 0; kb < 2; kb++) {
    const int ch = (kb << 2) | g;
    F16U bh[2];
#pragma unroll
    for (int b = 0; b < 2; b++) bh[b].s = fragld(BP, wj * 32 + b * 16 + lr, ch);
#pragma unroll
    for (int a = 0; a < 2; a++) {
      F16U ah; ah.s = fragld(AP, wi * 32 + a * 16 + lr, ch);
#pragma unroll
      for (int b = 0; b < 2; b++)
        acc[a][b] = __builtin_amdgcn_mfma_f32_16x16x32_f16(ah.h, bh[b].h, acc[a][b], 0, 0, 0);
    }
  }
}

// col-copy write, split bf16 (for symmetric S3: col-copy == row-major)
__device__ __forceinline__ void pack_col(u16* Ch, u16* Cl, const f32x4 acc[2][2],
                                         int wi, int wj, int g, int lr) {
#pragma unroll
  for (int a = 0; a < 2; a++) {
    const int r0 = wi * 32 + a * 16 + g * 4;
#pragma unroll
    for (int b = 0; b < 2; b++) {
      const int c = wj * 32 + b * 16 + lr;
      uint2 h, l;
      split4(acc[a][b][0], acc[a][b][1], acc[a][b][2], acc[a][b][3], h, l);
      const int ad = (c << 6) | (((((r0 >> 3)) ^ (c & 7)) << 3) | (r0 & 7));
      *(uint2*)(Ch + ad) = h;
      *(uint2*)(Cl + ad) = l;
    }
  }
}

// col-copy write, single fp16 plane, scaled
__device__ __forceinline__ void pack_colh(u16* C, const f32x4 acc[2][2], float sc,
                                          int wi, int wj, int g, int lr) {
#pragma unroll
  for (int a = 0; a < 2; a++) {
    const int r0 = wi * 32 + a * 16 + g * 4;
#pragma unroll
    for (int b = 0; b < 2; b++) {
      const int c = wj * 32 + b * 16 + lr;
      uint2 h;
      h.x = pkh(sc * acc[a][b][0], sc * acc[a][b][1]);
      h.y = pkh(sc * acc[a][b][2], sc * acc[a][b][3]);
      const int ad = (c << 6) | (((((r0 >> 3)) ^ (c & 7)) << 3) | (r0 & 7));
      *(uint2*)(C + ad) = h;
    }
  }
}

// dual fp16 copies for squaring: Rrow (scalar b16 scatter) + Rcol (b64)
__device__ __forceinline__ void pack_dualh(u16* Rrow, u16* Rcol, const f32x4 acc[2][2],
                                           int wi, int wj, int g, int lr) {
#pragma unroll
  for (int a = 0; a < 2; a++) {
    const int r0 = wi * 32 + a * 16 + g * 4;
#pragma unroll
    for (int b = 0; b < 2; b++) {
      const int c = wj * 32 + b * 16 + lr;
      uint2 h;
      h.x = pkh(acc[a][b][0], acc[a][b][1]);
      h.y = pkh(acc[a][b][2], acc[a][b][3]);
      const int adc = (c << 6) | (((((r0 >> 3)) ^ (c & 7)) << 3) | (r0 & 7));
      *(uint2*)(Rcol + adc) = h;
      const u16 hv[4] = {(u16)h.x, (u16)(h.x >> 16), (u16)h.y, (u16)(h.y >> 16)};
#pragma unroll
      for (int i = 0; i < 4; i++) {
        const int r = r0 + i;
        const int adr = (r << 6) | ((((c >> 3) ^ (r & 7)) << 3) | (c & 7));
        Rrow[adr] = hv[i];
      }
    }
  }
}

__global__ __launch_bounds__(256, 4)
void expm_kernel(const float* __restrict__ v, float* __restrict__ out) {
  __shared__ __align__(16) u16 PAh[4096], PAl[4096];   // A split; later Rrow/Rcol
  __shared__ __align__(16) u16 PF2[4096], PF4[4096];   // v-stage / X2,X4 fp16 / S3 split
  __shared__ float red[4];
  const int tid = threadIdx.x;
  const int bid = blockIdx.x;
  const int l = tid & 63, w = tid >> 6;
  const int g = l >> 4, lr = l & 15;
  const int wi = w >> 1, wj = w & 1;

  // 1. stage v row (2016 floats, 8064B) into PF2
  {
    float* vb = (float*)PF2;
    const float* vr = v + (size_t)bid * KKc;
    for (int i = tid; i < KKc; i += 256) vb[i] = vr[i];
  }
  __syncthreads();

  // 2. build skew A (UNSCALED) into PAh/PAl (split bf16)
  {
    const float* vb = (const float*)PF2;
    const int arow = tid >> 2, q = tid & 3;
    float va[16];
#pragma unroll
    for (int j = 0; j < 16; j++) {
      const int c = q * 16 + j;
      float val = 0.f;
      if (arow < c)      val =  vb[(arow * (127 - arow)) / 2 + c - arow - 1];
      else if (arow > c) val = -vb[(c * (127 - c)) / 2 + arow - c - 1];
      va[j] = val;
    }
#pragma unroll
    for (int cc = 0; cc < 2; cc++) {
      const int ch = 2 * q + cc;
      const int ad = (arow << 6) | ((ch ^ (arow & 7)) << 3);
      unsigned hw[4], lw[4];
#pragma unroll
      for (int p = 0; p < 4; p++) {
        const float a = va[cc * 8 + 2 * p], b = va[cc * 8 + 2 * p + 1];
        float fa, fb;
        hw[p] = pk_hi(a, b, fa, fb);
        lw[p] = pk(a - fa, b - fb);
      }
      *(u32x4*)(PAh + ad) = (u32x4){hw[0], hw[1], hw[2], hw[3]};
      *(u32x4*)(PAl + ad) = (u32x4){lw[0], lw[1], lw[2], lw[3]};
    }
  }
  __syncthreads();   // A planes ready; all reads of v-stage (PF2) done

  const f32x4 zz = {0.f, 0.f, 0.f, 0.f};
  f32x4 acc[2][2];

  // 3. A2 = A*A (3-pass split-bf16), keep f32 in rA2
  acc[0][0] = zz; acc[0][1] = zz; acc[1][0] = zz; acc[1][1] = zz;
  mat_mm<3, true>(PAh, PAl, PAh, PAl, acc, wi, wj, g, lr);
  f32x4 rA2[2][2];
  rA2[0][0] = acc[0][0]; rA2[0][1] = acc[0][1]; rA2[1][0] = acc[1][0]; rA2[1][1] = acc[1][1];

  // 4. s from ||A^2||_F (lambda <= ||A^2||_F^{1/2}), theta = 2
  {
    float fs = 0.f;
#pragma unroll
    for (int a = 0; a < 2; a++)
#pragma unroll
      for (int b = 0; b < 2; b++)
#pragma unroll
        for (int i = 0; i < 4; i++) fs = fmaf(rA2[a][b][i], rA2[a][b][i], fs);
#pragma unroll
    for (int k = 1; k < 64; k <<= 1) fs += __shfl_xor(fs, k, 64);
    if (l == 0) red[w] = fs;
  }
  __syncthreads();
  const float nf4 = red[0] + red[1] + red[2] + red[3];  // = ||A^2||_F^2
  int s = 0;
  if (nf4 > 16.f) {
    s = (int)ceilf(0.25f * log2f(nf4) - 1.0f);
    if (s < 0) s = 0;
    if (s > 15) s = 15;
  }
  const float t = exp2f(-(float)s);
  const float t2 = t * t;
  const float e2 = 0.5f * t2;
  const float o3 = t * t2 / 6.f;

  // 5. E/S3 partials from rA2; pack X2 = t^2*A2 (fp16) into PF2
  f32x4 rE[2][2], rS3[2][2];
#pragma unroll
  for (int a = 0; a < 2; a++)
#pragma unroll
    for (int b = 0; b < 2; b++)
#pragma unroll
      for (int i = 0; i < 4; i++) {
        const int row = wi * 32 + a * 16 + g * 4 + i;
        const int col = wj * 32 + b * 16 + lr;
        const float dg = (row == col) ? 1.f : 0.f;
        rE[a][b][i]  = dg + e2 * rA2[a][b][i];
        rS3[a][b][i] = t * dg + o3 * rA2[a][b][i];
      }
  pack_colh(PF2, rA2, t2, wi, wj, g, lr);   // X2 symmetric
  __syncthreads();

  // 6. X4 = X2*X2 (fp16 1-pass) = t^4 A^4
  acc[0][0] = zz; acc[0][1] = zz; acc[1][0] = zz; acc[1][1] = zz;
  mat_mm1h(PF2, PF2, acc, wi, wj, g, lr);
#pragma unroll
  for (int a = 0; a < 2; a++)
#pragma unroll
    for (int b = 0; b < 2; b++)
#pragma unroll
      for (int i = 0; i < 4; i++) {
        rE[a][b][i]  += (1.f / 24.f) * acc[a][b][i];
        rS3[a][b][i] += (t / 120.f) * acc[a][b][i];
      }
  pack_colh(PF4, acc, 1.f, wi, wj, g, lr);  // X4 symmetric
  __syncthreads();

  // 7. X6 = X4*X2 (fp16 1-pass, acc-only)
  acc[0][0] = zz; acc[0][1] = zz; acc[1][0] = zz; acc[1][1] = zz;
  mat_mm1h(PF4, PF2, acc, wi, wj, g, lr);
#pragma unroll
  for (int a = 0; a < 2; a++)
#pragma unroll
    for (int b = 0; b < 2; b++)
#pragma unroll
      for (int i = 0; i < 4; i++) {
        rE[a][b][i]  += (1.f / 720.f) * acc[a][b][i];
        rS3[a][b][i] += (t / 5040.f) * acc[a][b][i];
      }

  // 8. X8 = X4*X4 (fp16 1-pass, acc-only); degree-9 odd term
  acc[0][0] = zz; acc[0][1] = zz; acc[1][0] = zz; acc[1][1] = zz;
  mat_mm1h(PF4, PF4, acc, wi, wj, g, lr);
#pragma unroll
  for (int a = 0; a < 2; a++)
#pragma unroll
    for (int b = 0; b < 2; b++)
#pragma unroll
      for (int i = 0; i < 4; i++) {
        rE[a][b][i]  += (1.f / 40320.f) * acc[a][b][i];
        rS3[a][b][i] += (t / 362880.f) * acc[a][b][i];
      }
  __syncthreads();   // all X2/X4 reads done before S3 overwrite

  // 9. pack S3 (split bf16, symmetric) into PF2/PF4
  pack_col(PF2, PF4, rS3, wi, wj, g, lr);
  __syncthreads();

  // 10. R0 = E + A*S3 (3-pass split-bf16)
  acc[0][0] = rE[0][0]; acc[0][1] = rE[0][1]; acc[1][0] = rE[1][0]; acc[1][1] = rE[1][1];
  mat_mm<3, false>(PAh, PAl, PF2, PF4, acc, wi, wj, g, lr);
  __syncthreads();   // A/S3 reads done before squaring overwrites PAh/PAl

  // 11. s squarings, fp16 1-pass: Rrow = PAl (row-major), Rcol = PAh (col-major)
  for (int it = 0; it < s; it++) {
    pack_dualh(PAl, PAh, acc, wi, wj, g, lr);
    __syncthreads();
    acc[0][0] = zz; acc[0][1] = zz; acc[1][0] = zz; acc[1][1] = zz;
    mat_mm1h(PAl, PAh, acc, wi, wj, g, lr);
    __syncthreads();
  }

  // 12. store result: DPP transpose -> coalesced float4
  float* ob = out + (size_t)bid * 4096;
#pragma unroll
  for (int a = 0; a < 2; a++)
#pragma unroll
    for (int b = 0; b < 2; b++) {
      float tt[4] = {acc[a][b][0], acc[a][b][1], acc[a][b][2], acc[a][b][3]};
      transpose16(tt, l);
      const int row = wi * 32 + a * 16 + (l >> 2);
      const int c0 = wj * 32 + b * 16 + (l & 3) * 4;
      *(float4*)(ob + row * 64 + c0) = make_float4(tt[0], tt[1], tt[2], tt[3]);
    }
}

extern "C" void kernel_launch(void* const* d_in, const int* in_sizes, int n_in,
                              void* d_out, int out_size, void* d_ws, size_t ws_size,
                              hipStream_t stream) {
  const float* x = (const float*)d_in[0];
  const float* W = (const float*)d_in[1];
  const float* bias = (const float*)d_in[2];
  float* out = (float*)d_out;
  char* ws = (char*)d_ws;
  float* v = (float*)ws;

  const size_t V_BYTES  = (size_t)BB * KKc * 4;
  const size_t XH_ELEMS = (size_t)BB * NF;
  const size_t WH_ELEMS = (size_t)2048 * NF;
  const size_t NEED = V_BYTES + 2 * XH_ELEMS * 2 + 2 * WH_ELEMS * 2;

  if (ws_size >= NEED) {
    u16* xh = (u16*)(ws + V_BYTES);
    u16* xl = xh + XH_ELEMS;
    u16* wh = xl + XH_ELEMS;
    u16* wlp = wh + WH_ELEMS;
    silu_split_kernel<<<dim3(BB * NF / 4 / 256), dim3(256), 0, stream>>>(x, xh, xl);
    wsplit_kernel<<<dim3(2048 * NF / 4 / 256), dim3(256), 0, stream>>>(W, wh, wlp);
    gemm_mfma_kernel<<<dim3(16, 64), dim3(256), 0, stream>>>(xh, xl, wh, wlp, bias, v);
  } else {
    dim3 g1((KKc + BN - 1) / BN, BB / BM);
    gemm_silu_kernel<<<g1, dim3(256), 0, stream>>>(x, W, bias, v);
  }
  expm_kernel<<<dim3(BB), dim3(256), 0, stream>>>(v, out);
}